// Round 4
// baseline (122.797 us; speedup 1.0000x reference)
//
#include <hip/hip_runtime.h>

// Problem constants (B=1)
constexpr int C = 32, H = 256, W = 512, K = 10;
constexpr int HW = H * W;               // 131072
constexpr float TEMP = 10000.0f;

// -------- transpose right: CHW f32 -> HWC f32 (pixel-major) ---------------
__global__ __launch_bounds__(256) void conv_right_hwc(
    const float* __restrict__ in, float* __restrict__ out)
{
    __shared__ float t[C][129];          // +1 pad: conflict-free both phases
    const int base = blockIdx.x * 128;
    const int tid = threadIdx.x;
    #pragma unroll
    for (int i = 0; i < 16; ++i) {       // load 32ch x 128px tile, coalesced
        int lin = i * 256 + tid;
        int c = lin >> 7, px = lin & 127;
        t[c][px] = in[c * HW + base + px];
    }
    __syncthreads();
    #pragma unroll
    for (int i = 0; i < 16; ++i) {       // store HWC, fully coalesced
        int lin = i * 256 + tid;
        int px = lin >> 5, c = lin & 31;
        out[(base + px) * C + c] = t[c][px];
    }
}

// per-k bilinear fragment: 8 float4 corner loads + 4 weights
struct Frag {
    float4 a0, a1, b0, b1, d0, d1, e0, e1;
    float w00, w01, w10, w11;
};

__device__ __forceinline__ Frag load_frag(const float4* __restrict__ rb, int q,
                                          float lx, float ly, float ox, float oy)
{
    Frag f;
    // reference arithmetic chain, op-for-op (absmax 0.25 proven; do not simplify)
    float rx = fminf(fmaxf(lx - ox, 0.0f), (float)(W - 1));
    float ry = fminf(fmaxf(ly - oy, 0.0f), (float)(H - 1));
    float gx = (rx - (float)(W / 2)) / (float)(W / 2);
    float gy = (ry - (float)(H / 2)) / (float)(H / 2);
    float ix = ((gx + 1.0f) * (float)W - 1.0f) * 0.5f;
    float iy = ((gy + 1.0f) * (float)H - 1.0f) * 0.5f;

    float x0f = floorf(ix), y0f = floorf(iy);
    float wx1 = ix - x0f, wy1 = iy - y0f;
    float wx0 = 1.0f - wx1, wy0 = 1.0f - wy1;
    int x0 = (int)x0f, y0 = (int)y0f;

    // ix in [-0.5, 510.5], iy in [-0.5, 254.5] => x1,y1 ALWAYS in-bounds;
    // only the low-side validity masks survive.
    float ax = (x0 >= 0) ? wx0 : 0.0f;
    float ay = (y0 >= 0) ? wy0 : 0.0f;
    f.w00 = ax * ay;   f.w01 = wx1 * ay;
    f.w10 = ax * wy1;  f.w11 = wx1 * wy1;

    int xi0 = max(x0, 0), yi0 = max(y0, 0);
    int xi1 = x0 + 1,     yi1 = y0 + 1;    // in [0,W-1]/[0,H-1] by construction
    int r0 = yi0 * W, r1 = yi1 * W;
    // lane q reads float4 q (bytes [16q,16q+16)) and float4 4+q of each record:
    // the 4 lanes of a pixel group cover each 64-B sector contiguously.
    int b00 = (r0 + xi0) * 8 + q;
    int b01 = (r0 + xi1) * 8 + q;
    int b10 = (r1 + xi0) * 8 + q;
    int b11 = (r1 + xi1) * 8 + q;
    f.a0 = rb[b00]; f.a1 = rb[b00 + 4];
    f.b0 = rb[b01]; f.b1 = rb[b01 + 4];
    f.d0 = rb[b10]; f.d1 = rb[b10 + 4];
    f.e0 = rb[b11]; f.e1 = rb[b11 + 4];
    return f;
}

__device__ __forceinline__ float consume(const Frag& f, const float lf[8])
{
    float acc = 0.0f;
    acc += fabsf(lf[0] - (f.w00 * f.a0.x + f.w01 * f.b0.x + f.w10 * f.d0.x + f.w11 * f.e0.x));
    acc += fabsf(lf[1] - (f.w00 * f.a0.y + f.w01 * f.b0.y + f.w10 * f.d0.y + f.w11 * f.e0.y));
    acc += fabsf(lf[2] - (f.w00 * f.a0.z + f.w01 * f.b0.z + f.w10 * f.d0.z + f.w11 * f.e0.z));
    acc += fabsf(lf[3] - (f.w00 * f.a0.w + f.w01 * f.b0.w + f.w10 * f.d0.w + f.w11 * f.e0.w));
    acc += fabsf(lf[4] - (f.w00 * f.a1.x + f.w01 * f.b1.x + f.w10 * f.d1.x + f.w11 * f.e1.x));
    acc += fabsf(lf[5] - (f.w00 * f.a1.y + f.w01 * f.b1.y + f.w10 * f.d1.y + f.w11 * f.e1.y));
    acc += fabsf(lf[6] - (f.w00 * f.a1.z + f.w01 * f.b1.z + f.w10 * f.d1.z + f.w11 * f.e1.z));
    acc += fabsf(lf[7] - (f.w00 * f.a1.w + f.w01 * f.b1.w + f.w10 * f.d1.w + f.w11 * f.e1.w));
    return acc;
}

// -------- main: 4 lanes/pixel, 8 channels each, k+1 software pipeline -----
__global__ __launch_bounds__(256, 4) void disp_kernel_hwc(
    const float* __restrict__ lchw, const float* __restrict__ rhwc,
    const float* __restrict__ offx, const float* __restrict__ offy,
    float* __restrict__ out)
{
    const int tid = threadIdx.x;
    const int q = tid & 3;                        // channel quarter
    const int p = blockIdx.x * 64 + (tid >> 2);   // pixel id
    const int w = p & (W - 1);
    const int h = p >> 9;

    // left features from CHW, channel set matching the dense-sector partition:
    // j 0..3 -> channel 4q+j ; j 4..7 -> channel 16+4q+j
    float lf[8];
    #pragma unroll
    for (int j = 0; j < 4; ++j) lf[j]     = lchw[(4 * q + j) * HW + p];
    #pragma unroll
    for (int j = 0; j < 4; ++j) lf[4 + j] = lchw[(16 + 4 * q + j) * HW + p];

    float okx[K], oky[K];
    #pragma unroll
    for (int k = 0; k < K; ++k) {
        okx[k] = offx[k * HW + p];
        oky[k] = offy[k * HW + p];
    }

    const float lx = (float)w;
    const float ly = (float)h;   // ref clips y to W-1: no-op (H <= W)
    const float4* rb = (const float4*)rhwc;

    float s[K];
    Frag cur = load_frag(rb, q, lx, ly, okx[0], oky[0]);

    #pragma unroll
    for (int k = 0; k < K; ++k) {
        Frag nxt;
        if (k + 1 < K) nxt = load_frag(rb, q, lx, ly, okx[k + 1], oky[k + 1]);
        float acc = consume(cur, lf);
        acc += __shfl_xor(acc, 1);
        acc += __shfl_xor(acc, 2);
        s[k] = acc * (-TEMP / (float)C);   // -312.5 exact
        if (k + 1 < K) cur = nxt;
    }

    // softmax over K (redundant in all 4 lanes; lane q==0 writes)
    float m = s[0];
    #pragma unroll
    for (int k = 1; k < K; ++k) m = fmaxf(m, s[k]);
    float den = 0.0f, sx = 0.0f, sy = 0.0f;
    #pragma unroll
    for (int k = 0; k < K; ++k) {
        float e = __expf(s[k] - m);
        den += e;
        sx += okx[k] * e;
        sy += oky[k] * e;
    }
    float inv = 1.0f / den;
    if (q == 0) {
        out[p]      = sx * inv;
        out[HW + p] = sy * inv;
    }
}

// -------- fallback (round-1 kernel) if workspace too small ----------------
__global__ __launch_bounds__(256) void disp_kernel_chw(
    const float* __restrict__ left, const float* __restrict__ right,
    const float* __restrict__ offx, const float* __restrict__ offy,
    float* __restrict__ out)
{
    const int p = blockIdx.x * 256 + threadIdx.x;
    const int w = p & (W - 1);
    const int h = p >> 9;
    float lf[C];
    #pragma unroll
    for (int c = 0; c < C; ++c) lf[c] = left[c * HW + p];
    const float lx = (float)w, ly = (float)h;
    float s[K], okx[K], oky[K];
    #pragma unroll
    for (int k = 0; k < K; ++k) {
        const float ox = offx[k * HW + p], oy = offy[k * HW + p];
        okx[k] = ox; oky[k] = oy;
        float rx = fminf(fmaxf(lx - ox, 0.0f), (float)(W - 1));
        float ry = fminf(fmaxf(ly - oy, 0.0f), (float)(H - 1));
        float gx = (rx - 256.0f) / 256.0f, gy = (ry - 128.0f) / 128.0f;
        float ix = ((gx + 1.0f) * (float)W - 1.0f) * 0.5f;
        float iy = ((gy + 1.0f) * (float)H - 1.0f) * 0.5f;
        float x0f = floorf(ix), y0f = floorf(iy);
        float wx1 = ix - x0f, wy1 = iy - y0f;
        float wx0 = 1.0f - wx1, wy0 = 1.0f - wy1;
        int x0 = (int)x0f, y0 = (int)y0f, x1 = x0 + 1, y1 = y0 + 1;
        float vx0 = (x0 >= 0) ? 1.0f : 0.0f;
        float vy0 = (y0 >= 0) ? 1.0f : 0.0f;
        float w00 = wx0 * wy0 * vx0 * vy0, w01 = wx1 * wy0 * vy0;
        float w10 = wx0 * wy1 * vx0, w11 = wx1 * wy1;
        int xi0 = max(x0, 0), xi1 = x1;
        int yi0 = max(y0, 0), yi1 = y1;
        int i00 = yi0 * W + xi0, i01 = yi0 * W + xi1;
        int i10 = yi1 * W + xi0, i11 = yi1 * W + xi1;
        float acc = 0.0f;
        #pragma unroll
        for (int c = 0; c < C; ++c) {
            const float* rc = right + c * HW;
            acc += fabsf(lf[c] - (w00 * rc[i00] + w01 * rc[i01]
                                + w10 * rc[i10] + w11 * rc[i11]));
        }
        s[k] = acc * (-TEMP / (float)C);
    }
    float m = s[0];
    #pragma unroll
    for (int k = 1; k < K; ++k) m = fmaxf(m, s[k]);
    float den = 0.0f, sx = 0.0f, sy = 0.0f;
    #pragma unroll
    for (int k = 0; k < K; ++k) {
        float e = __expf(s[k] - m);
        den += e; sx += okx[k] * e; sy += oky[k] * e;
    }
    float inv = 1.0f / den;
    out[p] = sx * inv;
    out[HW + p] = sy * inv;
}

extern "C" void kernel_launch(void* const* d_in, const int* in_sizes, int n_in,
                              void* d_out, int out_size, void* d_ws, size_t ws_size,
                              hipStream_t stream) {
    const float* left  = (const float*)d_in[0];
    const float* right = (const float*)d_in[1];
    const float* offx  = (const float*)d_in[2];
    const float* offy  = (const float*)d_in[3];
    float* out = (float*)d_out;

    const size_t need = (size_t)HW * C * sizeof(float);   // 16 MB
    if (ws_size >= need) {
        float* rhwc = (float*)d_ws;
        conv_right_hwc<<<HW / 128, 256, 0, stream>>>(right, rhwc);
        disp_kernel_hwc<<<HW / 64, 256, 0, stream>>>(left, rhwc, offx, offy, out);
    } else {
        disp_kernel_chw<<<HW / 256, 256, 0, stream>>>(left, right, offx, offy, out);
    }
}